// Round 2
// baseline (269.972 us; speedup 1.0000x reference)
//
#include <hip/hip_runtime.h>

// Reference: x (16,192,128) f32, W (2,1), b (2,), T=25
// out[b, 0:26, :]            = x[b, 0:26, :]
// out[b, 26 + i*L + l, e]    = xp + (xi - xp) * sigmoid(-(x[b,l,e]*dW + dB))
//   where xi = x[b, 26+i, e], xp = x[b, 1+i, e],  i in [0,166), l in [0,192)
constexpr int Bn = 16;
constexpr int L  = 192;
constexpr int E  = 128;
constexpr int T  = 25;
constexpr int NI = L - T - 1;               // 166
constexpr int ROWS_OUT = (T + 1) + NI * L;  // 31898
constexpr int E4 = E / 4;                   // 32 float4 per row
constexpr int PREF_PER_B = (T + 1) * E4;    // 832 float4 prefix per batch

constexpr unsigned BODY_F4  = (unsigned)Bn * NI * L * E4;  // 16,293,888
constexpr unsigned PREF_F4  = (unsigned)Bn * PREF_PER_B;   // 13,312
constexpr unsigned TOTAL_F4 = BODY_F4 + PREF_F4;           // 16,307,200

typedef float f4 __attribute__((ext_vector_type(4)));

// Fill-shaped fused kernel: flat grid-stride over all output float4s.
// Rationale: the harness fill kernel proves 6.25 TB/s pure-write is reachable
// with a low-VGPR homogeneous streaming structure. The previous per-(b,i)
// block kernel (96 VGPRs preloaded, 4 wg/CU, lockstep load-phase/store-phase)
// ran at ~2.75 TB/s. This kernel mimics the fill: ~50 VGPR, 24 waves/CU,
// continuous interleaved L2-read + NT-store stream. All reads (x = 1.57 MB)
// are L2-resident on every XCD; sigmoid recomputed inline (trans-pipe, ~4 us
// chip-wide). HBM traffic = writes only (261 MB -> ~42 us floor).
__global__ __launch_bounds__(256, 6) void fused_kernel(
    const float* __restrict__ x,
    const float* __restrict__ W,
    const float* __restrict__ bv,
    float* __restrict__ out)
{
    const float dw = W[1] - W[0];
    const float db = bv[1] - bv[0];
    const f4* __restrict__ xv4 = (const f4*)x;
    f4* __restrict__ ov4 = (f4*)out;

    const unsigned stride = gridDim.x * 256u;
    for (unsigned g = blockIdx.x * 256u + threadIdx.x; g < TOTAL_F4; g += stride) {
        if (g < BODY_F4) {
            // g = ((b*NI + i)*L + l)*32 + e4
            const unsigned e4   = g & (E4 - 1);
            const unsigned rest = g >> 5;            // (b*NI + i)*L + l
            const unsigned l    = rest % L;          // magic-mul
            const unsigned bi   = rest / L;
            const unsigned i    = bi % NI;           // magic-mul
            const unsigned b    = bi / NI;

            const f4 xv = xv4[(b * L + l) * E4 + e4];          // sigmoid input
            const f4 xp = xv4[(b * L + 1 + i) * E4 + e4];      // past row
            const f4 xi = xv4[(b * L + T + 1 + i) * E4 + e4];  // current row

            f4 o;
            o.x = fmaf(xi.x - xp.x, __builtin_amdgcn_rcpf(1.0f + __expf(fmaf(xv.x, dw, db))), xp.x);
            o.y = fmaf(xi.y - xp.y, __builtin_amdgcn_rcpf(1.0f + __expf(fmaf(xv.y, dw, db))), xp.y);
            o.z = fmaf(xi.z - xp.z, __builtin_amdgcn_rcpf(1.0f + __expf(fmaf(xv.z, dw, db))), xp.z);
            o.w = fmaf(xi.w - xp.w, __builtin_amdgcn_rcpf(1.0f + __expf(fmaf(xv.w, dw, db))), xp.w);

            // dst_f4 = (b*ROWS_OUT + 26 + i*L + l)*32 + e4 = g + (b+1)*832
            __builtin_nontemporal_store(o, &ov4[g + (b + 1u) * PREF_PER_B]);
        } else {
            // prefix copy: out[b, 0:26, :] = x[b, 0:26, :]
            const unsigned p = g - BODY_F4;
            const unsigned b = p / PREF_PER_B;       // magic-mul
            const unsigned r = p % PREF_PER_B;
            const f4 v = xv4[b * (L * E4) + r];
            __builtin_nontemporal_store(v, &ov4[(size_t)b * (ROWS_OUT * E4) + r]);
        }
    }
}

extern "C" void kernel_launch(void* const* d_in, const int* in_sizes, int n_in,
                              void* d_out, int out_size, void* d_ws, size_t ws_size,
                              hipStream_t stream) {
    const float* x  = (const float*)d_in[0];
    const float* W  = (const float*)d_in[1];
    const float* bv = (const float*)d_in[2];
    float* out = (float*)d_out;

    // ~2048 blocks, grid-stride (~31 f4 per thread). Fill-like launch shape.
    const int grid = 2048;
    fused_kernel<<<grid, 256, 0, stream>>>(x, W, bv, out);
}

// Round 3
// 262.956 us; speedup vs baseline: 1.0267x; 1.0267x over previous
//
#include <hip/hip_runtime.h>

// Reference: x (16,192,128) f32, W (2,1), b (2,), T=25
// out[b, 0:26, :]            = x[b, 0:26, :]
// out[b, 26 + i*L + l, e]    = xp + (xi - xp) * sigmoid(-(x[b,l,e]*dW + dB))
//   where xi = x[b, 26+i, e], xp = x[b, 1+i, e],  i in [0,166), l in [0,192)
constexpr int Bn = 16;
constexpr int L  = 192;
constexpr int E  = 128;
constexpr int T  = 25;
constexpr int NI = L - T - 1;               // 166
constexpr int ROWS_OUT = (T + 1) + NI * L;  // 31898
constexpr int E4 = E / 4;                   // 32 float4 per row
constexpr int PREF_PER_B = (T + 1) * E4;    // 832 float4 prefix per batch

constexpr unsigned BODY_F4  = (unsigned)Bn * NI * L * E4;  // 16,293,888
constexpr unsigned PREF_F4  = (unsigned)Bn * PREF_PER_B;   // 13,312
constexpr unsigned TOTAL_F4 = BODY_F4 + PREF_F4;           // 16,307,200

typedef float f4 __attribute__((ext_vector_type(4)));

// Fused fill-shaped kernel, REGULAR stores (no nontemporal).
// Theory: NT stores force synchronous drain to HBM inside our kernel's
// window (4.8 TB/s effective); the harness fill's regular stores hit
// 6.25 TB/s with the 256 MB MALL absorbing the stream. Output = 261 MB.
// Reads: x = 1.57 MB, L2-resident per XCD; ~783 MB L2-read demand = 23 us
// at 34.5 TB/s — under the 42 us HBM write floor, so not the limit.
// exp folding: sigmoid(-(x*dw+db)) = rcp(1 + exp2(x*dw2 + db2)),
// dw2 = dw*log2(e), db2 = db*log2(e) — saves one v_mul per element.
__global__ __launch_bounds__(256, 6) void fused_kernel(
    const float* __restrict__ x,
    const float* __restrict__ W,
    const float* __restrict__ bv,
    float* __restrict__ out)
{
    constexpr float LOG2E = 1.44269504088896340736f;
    const float dw2 = (W[1] - W[0]) * LOG2E;
    const float db2 = (bv[1] - bv[0]) * LOG2E;
    const f4* __restrict__ xv4 = (const f4*)x;
    f4* __restrict__ ov4 = (f4*)out;

    const unsigned stride = gridDim.x * 256u;
    for (unsigned g = blockIdx.x * 256u + threadIdx.x; g < TOTAL_F4; g += stride) {
        if (g < BODY_F4) {
            // g = ((b*NI + i)*L + l)*32 + e4
            const unsigned e4   = g & (E4 - 1);
            const unsigned rest = g >> 5;            // (b*NI + i)*L + l
            const unsigned l    = rest % L;          // magic-mul
            const unsigned bi   = rest / L;
            const unsigned i    = bi % NI;           // magic-mul
            const unsigned b    = bi / NI;

            const f4 xv = xv4[(b * L + l) * E4 + e4];          // sigmoid input
            const f4 xp = xv4[(b * L + 1 + i) * E4 + e4];      // past row
            const f4 xi = xv4[(b * L + T + 1 + i) * E4 + e4];  // current row

            f4 o;
            o.x = fmaf(xi.x - xp.x, __builtin_amdgcn_rcpf(1.0f + __builtin_amdgcn_exp2f(fmaf(xv.x, dw2, db2))), xp.x);
            o.y = fmaf(xi.y - xp.y, __builtin_amdgcn_rcpf(1.0f + __builtin_amdgcn_exp2f(fmaf(xv.y, dw2, db2))), xp.y);
            o.z = fmaf(xi.z - xp.z, __builtin_amdgcn_rcpf(1.0f + __builtin_amdgcn_exp2f(fmaf(xv.z, dw2, db2))), xp.z);
            o.w = fmaf(xi.w - xp.w, __builtin_amdgcn_rcpf(1.0f + __builtin_amdgcn_exp2f(fmaf(xv.w, dw2, db2))), xp.w);

            // dst_f4 = (b*ROWS_OUT + 26 + i*L + l)*32 + e4 = g + (b+1)*832
            ov4[g + (b + 1u) * PREF_PER_B] = o;      // regular store
        } else {
            // prefix copy: out[b, 0:26, :] = x[b, 0:26, :]
            const unsigned p = g - BODY_F4;
            const unsigned b = p / PREF_PER_B;       // magic-mul
            const unsigned r = p % PREF_PER_B;
            ov4[(size_t)b * (ROWS_OUT * E4) + r] = xv4[b * (L * E4) + r];
        }
    }
}

extern "C" void kernel_launch(void* const* d_in, const int* in_sizes, int n_in,
                              void* d_out, int out_size, void* d_ws, size_t ws_size,
                              hipStream_t stream) {
    const float* x  = (const float*)d_in[0];
    const float* W  = (const float*)d_in[1];
    const float* bv = (const float*)d_in[2];
    float* out = (float*)d_out;

    const int grid = 2048;   // 8 blocks/CU, grid-stride (~31 f4 per thread)
    fused_kernel<<<grid, 256, 0, stream>>>(x, W, bv, out);
}